// Round 6
// baseline (298.122 us; speedup 1.0000x reference)
//
#include <hip/hip_runtime.h>
#include <cstdint>
#include <cstddef>

#define NFEATS 128
#define NHIDS  128
#define NOUT   64
#define SB     256    // nodes per bucket (dst >> 8)
#define CHUNK  4096   // edges per chunk in the radix partition

using bf16x8 = __attribute__((ext_vector_type(8))) short;
using f32x4  = __attribute__((ext_vector_type(4))) float;
using u32x4  = __attribute__((ext_vector_type(4))) unsigned int;

__device__ inline unsigned short f2bf(float f) {           // round-to-nearest-even
    union { float f; unsigned int u; } v; v.f = f;
    unsigned int r = (v.u + 0x7FFFu + ((v.u >> 16) & 1u)) >> 16;
    return (unsigned short)r;
}
__device__ inline float bflo(unsigned int u) { return __uint_as_float(u << 16); }
__device__ inline float bfhi(unsigned int u) { return __uint_as_float(u & 0xFFFF0000u); }

// ---------------------------------------------------------------------------
// Launch 1: edge dtype detect (block 0) + weight pack + deg zeroing
// (blocks 1..64).
// ---------------------------------------------------------------------------
__global__ void detect_wpack(const void* __restrict__ p, int* __restrict__ flag,
                             long long n_nodes,
                             const float* __restrict__ W1, unsigned short* __restrict__ Wf1,
                             const float* __restrict__ W2, unsigned short* __restrict__ Wf2,
                             int* __restrict__ deg, int n) {
    if (blockIdx.x == 0) {
        if (threadIdx.x < 64) {
            const long long* q = (const long long*)p;
            long long v = q[threadIdx.x];
            int bad = (v < 0 || v >= n_nodes) ? 1 : 0;
            unsigned long long m = __ballot(bad);
            if (threadIdx.x == 0) *flag = (m != 0ULL) ? 1 : 0;
        }
        return;
    }
    int i = (blockIdx.x - 1) * 256 + threadIdx.x;      // [0, 16384)
    if (i < 128 * 128) {                               // W1: [128][128]
        int k = i >> 7, n2 = i & 127;
        Wf1[(((k >> 3) * 128) + n2) * 8 + (k & 7)] = f2bf(W1[i]);
    }
    if (i < 128 * 64) {                                // W2: [128][64]
        int k = i >> 6, n2 = i & 63;
        Wf2[(((k >> 3) * 64) + n2) * 8 + (k & 7)] = f2bf(W2[i]);
    }
    for (int j = i; j < n; j += 64 * 256)              // zero degree array
        deg[j] = 0;
}

// ---------------------------------------------------------------------------
// Phase 1a: per-(chunk,bucket) histogram + exact global degree counts.
// deg[dst] atomics make dinv computable BEFORE bucket_finalize, which
// unblocks overlapping the layer-1 GEMM with the CSR chain.
// ---------------------------------------------------------------------------
__global__ __launch_bounds__(512)
void hist_kernel(const void* __restrict__ edges, const int* __restrict__ flag,
                 int* __restrict__ histT, int* __restrict__ deg,
                 int ne, int nch, int nbkt) {
    __shared__ int h[1024];
    int c = blockIdx.x, t = threadIdx.x;              // blockDim = 512
    for (int i = t; i < nbkt; i += 512) h[i] = 0;
    __syncthreads();
    int beg = c * CHUNK, end = min(ne, beg + CHUNK);
    bool is32 = (*flag != 0);
    for (int i = beg + t; i < end; i += 512) {
        int d = is32 ? ((const int*)edges)[ne + i]
                     : (int)((const long long*)edges)[ne + i];
        atomicAdd(&h[d >> 8], 1);
        atomicAdd(&deg[d], 1);
    }
    __syncthreads();
    for (int i = t; i < nbkt; i += 512)
        histT[i * nch + c] = h[i];
}

// ---------------------------------------------------------------------------
// Exclusive scan over histT.  chunk_base computed inline by consumers:
// CB(i) = partial[i>>8] + incl[i] - histT[i].
// ---------------------------------------------------------------------------
__global__ void scan_block(const int* __restrict__ v, int* __restrict__ incl,
                           int* __restrict__ partial, int n) {
    __shared__ int sh[256];
    int t = threadIdx.x;
    int i = blockIdx.x * 256 + t;
    sh[t] = (i < n) ? v[i] : 0;
    __syncthreads();
    for (int off = 1; off < 256; off <<= 1) {
        int add = (t >= off) ? sh[t - off] : 0;
        __syncthreads();
        sh[t] += add;
        __syncthreads();
    }
    if (i < n) incl[i] = sh[t];
    if (t == 255) partial[blockIdx.x] = sh[255];
}

// ---------------------------------------------------------------------------
// Block 0: scan of partials.  Blocks 1..: deg -> dinv conversion (carrier).
// ---------------------------------------------------------------------------
__global__ __launch_bounds__(512)
void scan_partials_dinv(int* __restrict__ partial, int nb,
                        const int* __restrict__ deg, float* __restrict__ dinv, int n) {
    if (blockIdx.x != 0) {
        int i = (blockIdx.x - 1) * 512 + threadIdx.x;
        if (i < n) dinv[i] = rsqrtf((float)(deg[i] + 1));
        return;
    }
    __shared__ int sh[512];
    __shared__ int carry;
    int t = threadIdx.x;
    if (t == 0) carry = 0;
    __syncthreads();
    for (int base = 0; base < nb; base += 512) {
        int idx = base + t;
        sh[t] = (idx < nb) ? partial[idx] : 0;
        __syncthreads();
        for (int off = 1; off < 512; off <<= 1) {
            int add = (t >= off) ? sh[t - off] : 0;
            __syncthreads();
            sh[t] += add;
            __syncthreads();
        }
        int excl = carry + ((t == 0) ? 0 : sh[t - 1]);
        if (idx < nb) partial[idx] = excl;
        __syncthreads();
        if (t == 0) carry += sh[511];
        __syncthreads();
    }
}

// ---------------------------------------------------------------------------
// 512-thread (8-wave) GEMM tile: hs[r][c] = bf16(dinv[r] * sum_k bf16(X[r][k])
// * Wf[k][c]).  Same fragment layouts and kt accumulation order as the proven
// 256-thread gemm_mfma (wave wv owns rows wv*16..+15) -> bit-identical hs1.
// ---------------------------------------------------------------------------
__device__ __forceinline__ void gemm_tile_512(const float* __restrict__ Xin,
                                              const unsigned short* __restrict__ Wf,
                                              const float* __restrict__ dinv,
                                              unsigned short* __restrict__ hs,
                                              int nrows, int row0, char* smem) {
    constexpr int K = 128, NC = 128;
    unsigned short* Xl = (unsigned short*)smem;        // 16*128*8 ushorts = 32 KB

    const int tid = threadIdx.x;
    for (int i = tid; i < 128 * 32; i += 512) {        // stage X tile (f32->bf16)
        int r  = i >> 5;
        int c4 = i & 31;
        int gr = row0 + r;
        ushort4 v = make_ushort4(0, 0, 0, 0);
        if (gr < nrows) {
            float4 f = ((const float4*)(Xin + (size_t)gr * K))[c4];
            v.x = f2bf(f.x); v.y = f2bf(f.y); v.z = f2bf(f.z); v.w = f2bf(f.w);
        }
        int k   = c4 * 4;
        int grp = k >> 3;                              // kt*4 + q
        int j0  = k & 7;                               // 0 or 4
        *(ushort4*)(Xl + ((size_t)grp * 128 + r) * 8 + j0) = v;
    }
    __syncthreads();

    const int wv   = tid >> 6;                         // 0..7 -> 16-row block
    const int lane = tid & 63;
    const int m    = lane & 15;
    const int q    = lane >> 4;

    bf16x8 af[4];
#pragma unroll
    for (int kt = 0; kt < 4; ++kt)
        af[kt] = *(const bf16x8*)(Xl + (((kt * 4 + q) * 128) + wv * 16 + m) * 8);

    const int rbase = row0 + wv * 16 + q * 4;
    float dv[4];
#pragma unroll
    for (int i = 0; i < 4; ++i)
        dv[i] = (rbase + i < nrows) ? dinv[rbase + i] : 0.f;

#pragma unroll
    for (int nt = 0; nt < NC / 16; ++nt) {
        bf16x8 bfr[4];
#pragma unroll
        for (int kt = 0; kt < 4; ++kt)
            bfr[kt] = *(const bf16x8*)(Wf + (((size_t)(kt * 4 + q) * NC) + nt * 16 + m) * 8);
        f32x4 acc = {0.f, 0.f, 0.f, 0.f};
#pragma unroll
        for (int kt = 0; kt < 4; ++kt)
            acc = __builtin_amdgcn_mfma_f32_16x16x32_bf16(af[kt], bfr[kt], acc, 0, 0, 0);
#pragma unroll
        for (int i = 0; i < 4; ++i) {
            int g = rbase + i;
            if (g < nrows)
                hs[(size_t)g * NC + nt * 16 + m] = f2bf(acc[i] * dv[i]);
        }
    }
}

// ---------------------------------------------------------------------------
// Phase 1b: blocks [0,nch): LDS bucket sort + coalesced writes (chunk_base
// inline).  Blocks [nch,..): layer-1 GEMM tiles (dinv is ready; fills the
// CUs the scatter underfills -> GEMM rides for ~free).
// ---------------------------------------------------------------------------
__global__ __launch_bounds__(512)
void scatter_gemm(const void* __restrict__ edges, const int* __restrict__ flag,
                  const int* __restrict__ histT, const int* __restrict__ incl,
                  const int* __restrict__ partial,
                  unsigned int* __restrict__ ebuf,
                  int ne, int nch, int nbkt,
                  const float* __restrict__ x, const unsigned short* __restrict__ Wf1,
                  const float* __restrict__ dinv, unsigned short* __restrict__ hs1,
                  int nrows) {
    __shared__ __align__(16) char smem[32768];
    if ((int)blockIdx.x >= nch) {                      // GEMM carrier blocks
        gemm_tile_512(x, Wf1, dinv, hs1, nrows, ((int)blockIdx.x - nch) * 128, smem);
        return;
    }
    int*            cnt    = (int*)smem;                       //  2 KB
    int*            cursor = (int*)(smem + 2048);              //  2 KB
    int*            delta  = (int*)(smem + 4096);              //  2 KB
    unsigned int*   srt    = (unsigned int*)(smem + 6144);     // 16 KB
    unsigned short* bkl    = (unsigned short*)(smem + 22528);  //  8 KB

    int c = blockIdx.x, t = threadIdx.x;               // blockDim = 512
    if (t < nbkt) cnt[t] = 0;
    int cb = 0;
    if (t < nbkt) {
        int idx = t * nch + c;
        cb = partial[idx >> 8] + incl[idx] - histT[idx];
    }
    __syncthreads();

    int beg = c * CHUNK, end = min(ne, beg + CHUNK);
    int nloc = end - beg;
    bool is32 = (*flag != 0);

    unsigned int rec[8];
    int bk[8];
#pragma unroll
    for (int r = 0; r < 8; ++r) {
        int i = beg + t + r * 512;
        bk[r] = -1;
        if (i < end) {
            int s, d;
            if (is32) {
                s = ((const int*)edges)[i];
                d = ((const int*)edges)[ne + i];
            } else {
                s = (int)((const long long*)edges)[i];
                d = (int)((const long long*)edges)[ne + i];
            }
            rec[r] = ((unsigned int)s << 8) | (unsigned int)(d & (SB - 1));
            bk[r]  = d >> 8;
            atomicAdd(&cnt[bk[r]], 1);
        }
    }
    __syncthreads();

    int v0 = (t < nbkt) ? cnt[t] : 0;
    cursor[t] = v0;
    __syncthreads();
    for (int off = 1; off < 512; off <<= 1) {
        int add = (t >= off) ? cursor[t - off] : 0;
        __syncthreads();
        cursor[t] += add;
        __syncthreads();
    }
    int inc = cursor[t];
    __syncthreads();
    int lb = inc - v0;
    cursor[t] = lb;
    if (t < nbkt) delta[t] = cb - lb;
    __syncthreads();

#pragma unroll
    for (int r = 0; r < 8; ++r) {
        if (bk[r] >= 0) {
            int pos = atomicAdd(&cursor[bk[r]], 1);
            srt[pos] = rec[r];
            bkl[pos] = (unsigned short)bk[r];
        }
    }
    __syncthreads();

    for (int i = t; i < nloc; i += 512)
        ebuf[delta[bkl[i]] + i] = srt[i];
}

// ---------------------------------------------------------------------------
// Phase 2: per-bucket CSR finalize; LDS-staged coalesced csr_src write;
// chunk_base inline.  (dinv now produced earlier from atomic degrees.)
// ---------------------------------------------------------------------------
__global__ void bucket_finalize(const unsigned int* __restrict__ ebuf,
                                const int* __restrict__ histT, const int* __restrict__ inclG,
                                const int* __restrict__ partial,
                                int* __restrict__ row_ptr,
                                int* __restrict__ csr_src,
                                int n, int e, int nch, int nbkt) {
    __shared__ int deg[SB];
    __shared__ int incl[SB];
    __shared__ int cur[SB];
    __shared__ int stage[4608];                        // 18 KB staging
    __shared__ int sbase, sbend;
    int b = blockIdx.x, t = threadIdx.x;               // blockDim = SB = 256
    int node0 = b * SB;
    int nn = min(SB, n - node0);
    if (t == 0) {
        int i0 = b * nch;
        sbase = partial[i0 >> 8] + inclG[i0] - histT[i0];
        if (b == nbkt - 1) sbend = e;
        else {
            int i1 = (b + 1) * nch;
            sbend = partial[i1 >> 8] + inclG[i1] - histT[i1];
        }
    }
    deg[t] = 0;
    __syncthreads();
    int base = sbase, bend = sbend;

    for (int i = base + t; i < bend; i += SB)
        atomicAdd(&deg[ebuf[i] & (SB - 1)], 1);
    __syncthreads();

    incl[t] = deg[t];
    __syncthreads();
    for (int off = 1; off < SB; off <<= 1) {
        int add = (t >= off) ? incl[t - off] : 0;
        __syncthreads();
        incl[t] += add;
        __syncthreads();
    }
    int lrow = base + incl[t] - deg[t];
    cur[t] = lrow - base;                              // local cursor
    if (t < nn) row_ptr[node0 + t] = lrow;
    if (b == nbkt - 1 && t == 0) row_ptr[n] = e;
    __syncthreads();

    int cntE = bend - base;
    if (cntE <= 4608) {
        for (int i = base + t; i < bend; i += SB) {
            unsigned int r = ebuf[i];
            int pos = atomicAdd(&cur[r & (SB - 1)], 1);
            stage[pos] = (int)(r >> 8);
        }
        __syncthreads();
        for (int i = t; i < cntE; i += SB)             // coalesced linear store
            csr_src[base + i] = stage[i];
    } else {
        for (int i = base + t; i < bend; i += SB) {
            unsigned int r = ebuf[i];
            int pos = atomicAdd(&cur[r & (SB - 1)], 1);
            csr_src[base + pos] = (int)(r >> 8);
        }
    }
}

// ---------------------------------------------------------------------------
// FUSED layer-1 aggregate + layer-2 GEMM (at the random-gather fetch-path
// floor: 186 MB FETCH at ~3.15 TB/s — unchanged).
// ---------------------------------------------------------------------------
__launch_bounds__(256)
__global__ void aggregate_fused_l1(const int* __restrict__ row_ptr,
                                   const int* __restrict__ csr_src,
                                   const uint4* __restrict__ hsu,
                                   const float* __restrict__ dinv,
                                   const float* __restrict__ b,
                                   const unsigned short* __restrict__ Wf2,
                                   unsigned short* __restrict__ hs2, int n) {
    constexpr int TPN = 16;
    constexpr int NPB = 16;
    constexpr int CH  = 16;

    __shared__ __align__(16) unsigned short h1t[16 * 136];   // 272 B/row
    __shared__ float dl[16];
    __shared__ __align__(16) unsigned short outt[16 * 64];   // 2 KB

    const int node0 = blockIdx.x * NPB;
    const int nl    = threadIdx.x / TPN;
    const int t     = threadIdx.x % TPN;
    const int node  = min(node0 + nl, n - 1);
    const int lane  = threadIdx.x & 63;
    const int gb    = lane & ~(TPN - 1);

    uint4 u = hsu[(size_t)node * TPN + t];            // self-loop term
    float a[8];
    a[0] = bflo(u.x); a[1] = bfhi(u.x); a[2] = bflo(u.y); a[3] = bfhi(u.y);
    a[4] = bflo(u.z); a[5] = bfhi(u.z); a[6] = bflo(u.w); a[7] = bfhi(u.w);

    int beg = row_ptr[node], end = row_ptr[node + 1];

    if (beg < end) {
        const u32x4* hb = (const u32x4*)hsu;
        u32x4 v[CH];
        int sva;
        int base = beg;

        {
            const int* pc0 = csr_src + min(base + t, end - 1);
            asm volatile("global_load_dword %0, %1, off" : "=&v"(sva) : "v"(pc0));
        }
        asm volatile("s_waitcnt vmcnt(0)");
        __builtin_amdgcn_sched_barrier(0);

        while (true) {
            int rem = min(CH, end - base);

#pragma unroll
            for (int j = 0; j < CH; ++j) {
                int jj = min(j, rem - 1);
                int sj = __shfl(sva, gb + jj, 64);
                const u32x4* p = hb + (size_t)sj * TPN + t;
                asm volatile("global_load_dwordx4 %0, %1, off" : "=&v"(v[j]) : "v"(p));
            }

            int  nbase = base + CH;
            bool more  = nbase < end;
            if (more) {
                const int* pc0 = csr_src + min(nbase + t, end - 1);
                asm volatile("global_load_dword %0, %1, off" : "=&v"(sva) : "v"(pc0));
                asm volatile("s_waitcnt vmcnt(1)");
            } else {
                asm volatile("s_waitcnt vmcnt(0)");
            }
            __builtin_amdgcn_sched_barrier(0);

#pragma unroll
            for (int j = 0; j < CH; ++j) {
                if (j < rem) {
                    unsigned int x0 = v[j][0], x1 = v[j][1], x2 = v[j][2], x3 = v[j][3];
                    a[0] += bflo(x0); a[1] += bfhi(x0);
                    a[2] += bflo(x1); a[3] += bfhi(x1);
                    a[4] += bflo(x2); a[5] += bfhi(x2);
                    a[6] += bflo(x3); a[7] += bfhi(x3);
                }
            }

            if (!more) break;
            base = nbase;
            asm volatile("s_waitcnt vmcnt(0)");
            __builtin_amdgcn_sched_barrier(0);
        }
    }

    float dvn = dinv[node];
    float4 b0 = ((const float4*)b)[2 * t];
    float4 b1 = ((const float4*)b)[2 * t + 1];
    float o[8];
    o[0] = a[0] * dvn + b0.x; o[1] = a[1] * dvn + b0.y;
    o[2] = a[2] * dvn + b0.z; o[3] = a[3] * dvn + b0.w;
    o[4] = a[4] * dvn + b1.x; o[5] = a[5] * dvn + b1.y;
    o[6] = a[6] * dvn + b1.z; o[7] = a[7] * dvn + b1.w;
#pragma unroll
    for (int j = 0; j < 8; ++j) o[j] = fmaxf(o[j], 0.f);

    uint4 ov;
    ov.x = (unsigned int)f2bf(o[0]) | ((unsigned int)f2bf(o[1]) << 16);
    ov.y = (unsigned int)f2bf(o[2]) | ((unsigned int)f2bf(o[3]) << 16);
    ov.z = (unsigned int)f2bf(o[4]) | ((unsigned int)f2bf(o[5]) << 16);
    ov.w = (unsigned int)f2bf(o[6]) | ((unsigned int)f2bf(o[7]) << 16);
    *(uint4*)((char*)h1t + (size_t)nl * 272 + t * 16) = ov;
    if (t == 0) dl[nl] = dvn;
    __syncthreads();

    {
        const int wv = threadIdx.x >> 6;
        const int m  = lane & 15;
        const int q  = lane >> 4;

        f32x4 acc = {0.f, 0.f, 0.f, 0.f};
#pragma unroll
        for (int kt = 0; kt < 4; ++kt) {
            bf16x8 af  = *(const bf16x8*)((const char*)h1t + (size_t)m * 272 + q * 16 + kt * 64);
            bf16x8 bfr = *(const bf16x8*)(Wf2 + (((size_t)(kt * 4 + q) * 64) + wv * 16 + m) * 8);
            acc = __builtin_amdgcn_mfma_f32_16x16x32_bf16(af, bfr, acc, 0, 0, 0);
        }
#pragma unroll
        for (int i = 0; i < 4; ++i) {
            int nd = q * 4 + i;
            outt[nd * 64 + wv * 16 + m] = f2bf(acc[i] * dl[nd]);
        }
    }
    __syncthreads();

    {
        int i = threadIdx.x;
        if (i < 128) {
            int gnode = node0 + (i >> 3);
            if (gnode < n)
                ((uint4*)hs2)[(size_t)gnode * 8 + (i & 7)] = ((const uint4*)outt)[i];
        }
    }
}

// ---------------------------------------------------------------------------
// Layer-2 aggregate (F=64), 16-deep asm gather pipeline.
// ---------------------------------------------------------------------------
template <int F, bool RELU, bool OUTBF>
__launch_bounds__(256)
__global__ void aggregate_bf16(const int* __restrict__ row_ptr,
                               const int* __restrict__ csr_src,
                               const uint4* __restrict__ hsu,
                               const float* __restrict__ dinv,
                               const float* __restrict__ b,
                               void* __restrict__ out, int n) {
    constexpr int TPN  = F / 8;
    constexpr int NPB  = 256 / TPN;
    constexpr int CH   = 16;
    constexpr int NCSR = CH / TPN;
    int node = blockIdx.x * NPB + threadIdx.x / TPN;
    int t    = threadIdx.x % TPN;
    if (node >= n) return;
    const int lane = threadIdx.x & 63;
    const int gb   = lane & ~(TPN - 1);

    uint4 u = hsu[(size_t)node * TPN + t];
    float a[8];
    a[0] = bflo(u.x); a[1] = bfhi(u.x); a[2] = bflo(u.y); a[3] = bfhi(u.y);
    a[4] = bflo(u.z); a[5] = bfhi(u.z); a[6] = bflo(u.w); a[7] = bfhi(u.w);

    int beg = row_ptr[node], end = row_ptr[node + 1];

    if (beg < end) {
        const u32x4* hb = (const u32x4*)hsu;
        u32x4 v[CH];
        int sva, svb;
        int base = beg;

        {
            const int* pc0 = csr_src + min(base + t, end - 1);
            asm volatile("global_load_dword %0, %1, off" : "=&v"(sva) : "v"(pc0));
            if (NCSR == 2) {
                const int* pc1 = csr_src + min(base + TPN + t, end - 1);
                asm volatile("global_load_dword %0, %1, off" : "=&v"(svb) : "v"(pc1));
            }
        }
        asm volatile("s_waitcnt vmcnt(0)");
        __builtin_amdgcn_sched_barrier(0);

        while (true) {
            int rem = min(CH, end - base);

#pragma unroll
            for (int j = 0; j < CH; ++j) {
                int jj = min(j, rem - 1);
                int sj;
                if (TPN == 16) {
                    sj = __shfl(sva, gb + jj, 64);
                } else {
                    int s0 = __shfl(sva, gb + (jj & 7), 64);
                    int s1 = __shfl(svb, gb + (jj & 7), 64);
                    sj = (jj < 8) ? s0 : s1;
                }
                const u32x4* p = hb + (size_t)sj * TPN + t;
                asm volatile("global_load_dwordx4 %0, %1, off" : "=&v"(v[j]) : "v"(p));
            }

            int  nbase = base + CH;
            bool more  = nbase < end;
            if (more) {
                const int* pc0 = csr_src + min(nbase + t, end - 1);
                asm volatile("global_load_dword %0, %1, off" : "=&v"(sva) : "v"(pc0));
                if (NCSR == 2) {
                    const int* pc1 = csr_src + min(nbase + TPN + t, end - 1);
                    asm volatile("global_load_dword %0, %1, off" : "=&v"(svb) : "v"(pc1));
                }
                if (NCSR == 1) asm volatile("s_waitcnt vmcnt(1)");
                else           asm volatile("s_waitcnt vmcnt(2)");
            } else {
                asm volatile("s_waitcnt vmcnt(0)");
            }
            __builtin_amdgcn_sched_barrier(0);

#pragma unroll
            for (int j = 0; j < CH; ++j) {
                if (j < rem) {
                    unsigned int x0 = v[j][0], x1 = v[j][1], x2 = v[j][2], x3 = v[j][3];
                    a[0] += bflo(x0); a[1] += bfhi(x0);
                    a[2] += bflo(x1); a[3] += bfhi(x1);
                    a[4] += bflo(x2); a[5] += bfhi(x2);
                    a[6] += bflo(x3); a[7] += bfhi(x3);
                }
            }

            if (!more) break;
            base = nbase;
            asm volatile("s_waitcnt vmcnt(0)");
            __builtin_amdgcn_sched_barrier(0);
        }
    }

    float dvn = dinv[node];
    float4 b0 = ((const float4*)b)[2 * t];
    float4 b1 = ((const float4*)b)[2 * t + 1];
    float o[8];
    o[0] = a[0] * dvn + b0.x; o[1] = a[1] * dvn + b0.y;
    o[2] = a[2] * dvn + b0.z; o[3] = a[3] * dvn + b0.w;
    o[4] = a[4] * dvn + b1.x; o[5] = a[5] * dvn + b1.y;
    o[6] = a[6] * dvn + b1.z; o[7] = a[7] * dvn + b1.w;
    if (RELU) {
#pragma unroll
        for (int j = 0; j < 8; ++j) o[j] = fmaxf(o[j], 0.f);
    }
    if (OUTBF) {
        uint4 ov;
        ov.x = (unsigned int)f2bf(o[0]) | ((unsigned int)f2bf(o[1]) << 16);
        ov.y = (unsigned int)f2bf(o[2]) | ((unsigned int)f2bf(o[3]) << 16);
        ov.z = (unsigned int)f2bf(o[4]) | ((unsigned int)f2bf(o[5]) << 16);
        ov.w = (unsigned int)f2bf(o[6]) | ((unsigned int)f2bf(o[7]) << 16);
        ((uint4*)out)[(size_t)node * TPN + t] = ov;
    } else {
        float4* op = (float4*)out + (size_t)node * (F / 4) + 2 * t;
        op[0] = make_float4(o[0], o[1], o[2], o[3]);
        op[1] = make_float4(o[4], o[5], o[6], o[7]);
    }
}

// ---------------------------------------------------------------------------
extern "C" void kernel_launch(void* const* d_in, const int* in_sizes, int n_in,
                              void* d_out, int out_size, void* d_ws, size_t ws_size,
                              hipStream_t stream) {
    const void*  edge = d_in[0];
    const float* x    = (const float*)d_in[1];
    const float* W1   = (const float*)d_in[2];
    const float* b1   = (const float*)d_in[3];
    const float* W2   = (const float*)d_in[4];
    const float* b2   = (const float*)d_in[5];
    float* out = (float*)d_out;

    const int E    = in_sizes[0] / 2;
    const int N    = in_sizes[1] / NFEATS;
    const int NBKT = (N + SB - 1) / SB;        // 391
    const int NCH  = (E + CHUNK - 1) / CHUNK;  // 391
    const int M    = NBKT * NCH;

    char* w = (char*)d_ws;
    auto carve = [&](size_t bytes) { void* p = w; w += (bytes + 255) & ~(size_t)255; return p; };
    int*            flag       = (int*)           carve(256);
    int*            histT      = (int*)           carve(sizeof(int) * (size_t)M);
    int*            incl       = (int*)           carve(sizeof(int) * (size_t)M);
    int*            partial    = (int*)           carve(sizeof(int) * 4096);
    int*            row_ptr    = (int*)           carve(sizeof(int) * ((size_t)N + 1));
    int*            deg        = (int*)           carve(sizeof(int) * (size_t)N);
    float*          dinv       = (float*)         carve(sizeof(float) * (size_t)N);
    unsigned int*   ebuf       = (unsigned int*)  carve(sizeof(int) * (size_t)E);
    int*            csr_src    = (int*)           carve(sizeof(int) * (size_t)E);
    unsigned short* Wf1        = (unsigned short*)carve(2 * (size_t)NFEATS * NHIDS);
    unsigned short* Wf2        = (unsigned short*)carve(2 * (size_t)NHIDS * NOUT);
    unsigned short* hs1        = (unsigned short*)carve(2 * (size_t)N * NHIDS);
    unsigned short* hs2        = (unsigned short*)carve(2 * (size_t)N * NOUT);

    const int nbS = (M + 255) / 256;
    const int GB  = (N + 127) / 128;           // 782 gemm tiles

    // 1. detect + weight pack + deg zeroing (fused)
    detect_wpack<<<65, 256, 0, stream>>>(edge, flag, (long long)N, W1, Wf1, W2, Wf2,
                                         deg, N);

    // 2. chunk histograms + exact degree atomics
    hist_kernel<<<NCH, 512, 0, stream>>>(edge, flag, histT, deg, E, NCH, NBKT);

    // 3-4. scan; partials scan + dinv conversion carrier
    scan_block<<<nbS, 256, 0, stream>>>(histT, incl, partial, M);
    scan_partials_dinv<<<1 + (N + 511) / 512, 512, 0, stream>>>(partial, nbS,
                                                                deg, dinv, N);

    // 5. LDS bucket-sort partition + layer-1 GEMM overlapped (dinv ready)
    scatter_gemm<<<NCH + GB, 512, 0, stream>>>(edge, flag, histT, incl, partial,
                                               ebuf, E, NCH, NBKT,
                                               x, Wf1, dinv, hs1, N);

    // 6. per-bucket CSR finalize
    bucket_finalize<<<NBKT, SB, 0, stream>>>(ebuf, histT, incl, partial,
                                             row_ptr, csr_src, N, E, NCH, NBKT);

    // 7. fused: layer-1 aggregate + ReLU + layer-2 GEMM -> hs2
    aggregate_fused_l1<<<(N + 15) / 16, 256, 0, stream>>>(
        row_ptr, csr_src, (const uint4*)hs1, dinv, b1, Wf2, hs2, N);

    // 8. layer-2 aggregate -> out
    {
        constexpr int NPB = 256 / (NOUT / 8);
        aggregate_bf16<NOUT, false, false><<<(N + NPB - 1) / NPB, 256, 0, stream>>>(
            row_ptr, csr_src, (const uint4*)hs2, dinv, b2, out, N);
    }
}

// Round 7
// 290.158 us; speedup vs baseline: 1.0274x; 1.0274x over previous
//
#include <hip/hip_runtime.h>
#include <cstdint>
#include <cstddef>

#define NFEATS 128
#define NHIDS  128
#define NOUT   64
#define SB     256    // nodes per bucket (dst >> 8)
#define CHUNK  4096   // edges per chunk in the radix partition

using bf16x8 = __attribute__((ext_vector_type(8))) short;
using f32x4  = __attribute__((ext_vector_type(4))) float;
using u32x4  = __attribute__((ext_vector_type(4))) unsigned int;

__device__ inline unsigned short f2bf(float f) {           // round-to-nearest-even
    union { float f; unsigned int u; } v; v.f = f;
    unsigned int r = (v.u + 0x7FFFu + ((v.u >> 16) & 1u)) >> 16;
    return (unsigned short)r;
}
__device__ inline float bflo(unsigned int u) { return __uint_as_float(u << 16); }
__device__ inline float bfhi(unsigned int u) { return __uint_as_float(u & 0xFFFF0000u); }

// ---------------------------------------------------------------------------
// Launch 1: edge dtype detect (block 0) + weight pack (blocks 1..64).
// (R6 deg-zeroing removed: global degree atomics regressed hist 10->70 us.)
// ---------------------------------------------------------------------------
__global__ void detect_wpack(const void* __restrict__ p, int* __restrict__ flag,
                             long long n_nodes,
                             const float* __restrict__ W1, unsigned short* __restrict__ Wf1,
                             const float* __restrict__ W2, unsigned short* __restrict__ Wf2) {
    if (blockIdx.x == 0) {
        if (threadIdx.x < 64) {
            const long long* q = (const long long*)p;
            long long v = q[threadIdx.x];
            int bad = (v < 0 || v >= n_nodes) ? 1 : 0;
            unsigned long long m = __ballot(bad);
            if (threadIdx.x == 0) *flag = (m != 0ULL) ? 1 : 0;
        }
        return;
    }
    int i = (blockIdx.x - 1) * 256 + threadIdx.x;      // [0, 16384)
    if (i < 128 * 128) {                               // W1: [128][128]
        int k = i >> 7, n2 = i & 127;
        Wf1[(((k >> 3) * 128) + n2) * 8 + (k & 7)] = f2bf(W1[i]);
    }
    if (i < 128 * 64) {                                // W2: [128][64]
        int k = i >> 6, n2 = i & 63;
        Wf2[(((k >> 3) * 64) + n2) * 8 + (k & 7)] = f2bf(W2[i]);
    }
}

// ---------------------------------------------------------------------------
// Phase 1a: per-(chunk,bucket) histogram. histT[b*nch + c].
// ---------------------------------------------------------------------------
__global__ __launch_bounds__(512)
void hist_kernel(const void* __restrict__ edges, const int* __restrict__ flag,
                 int* __restrict__ histT, int ne, int nch, int nbkt) {
    __shared__ int h[1024];
    int c = blockIdx.x, t = threadIdx.x;              // blockDim = 512
    for (int i = t; i < nbkt; i += 512) h[i] = 0;
    __syncthreads();
    int beg = c * CHUNK, end = min(ne, beg + CHUNK);
    bool is32 = (*flag != 0);
    for (int i = beg + t; i < end; i += 512) {
        int d = is32 ? ((const int*)edges)[ne + i]
                     : (int)((const long long*)edges)[ne + i];
        atomicAdd(&h[d >> 8], 1);
    }
    __syncthreads();
    for (int i = t; i < nbkt; i += 512)
        histT[i * nch + c] = h[i];
}

// ---------------------------------------------------------------------------
// Exclusive scan over histT.  chunk_base computed inline by consumers:
// CB(i) = partial[i>>8] + incl[i] - histT[i].
// ---------------------------------------------------------------------------
__global__ void scan_block(const int* __restrict__ v, int* __restrict__ incl,
                           int* __restrict__ partial, int n) {
    __shared__ int sh[256];
    int t = threadIdx.x;
    int i = blockIdx.x * 256 + t;
    sh[t] = (i < n) ? v[i] : 0;
    __syncthreads();
    for (int off = 1; off < 256; off <<= 1) {
        int add = (t >= off) ? sh[t - off] : 0;
        __syncthreads();
        sh[t] += add;
        __syncthreads();
    }
    if (i < n) incl[i] = sh[t];
    if (t == 255) partial[blockIdx.x] = sh[255];
}

__global__ void scan_partials(int* partial, int nb) {
    __shared__ int sh[512];
    __shared__ int carry;
    int t = threadIdx.x;
    if (t == 0) carry = 0;
    __syncthreads();
    for (int base = 0; base < nb; base += 512) {
        int idx = base + t;
        sh[t] = (idx < nb) ? partial[idx] : 0;
        __syncthreads();
        for (int off = 1; off < 512; off <<= 1) {
            int add = (t >= off) ? sh[t - off] : 0;
            __syncthreads();
            sh[t] += add;
            __syncthreads();
        }
        int excl = carry + ((t == 0) ? 0 : sh[t - 1]);
        if (idx < nb) partial[idx] = excl;
        __syncthreads();
        if (t == 0) carry += sh[511];
        __syncthreads();
    }
}

// ---------------------------------------------------------------------------
// Phase 1b: LDS bucket sort + coalesced writes (chunk_base inline).
// ---------------------------------------------------------------------------
__global__ __launch_bounds__(512)
void scatter_chunks(const void* __restrict__ edges, const int* __restrict__ flag,
                    const int* __restrict__ histT, const int* __restrict__ incl,
                    const int* __restrict__ partial,
                    unsigned int* __restrict__ ebuf,
                    int ne, int nch, int nbkt) {
    __shared__ int cnt[512];
    __shared__ int cursor[512];
    __shared__ int delta[512];
    __shared__ unsigned int   srt[CHUNK];            // 16 KB
    __shared__ unsigned short bkl[CHUNK];            // 8 KB
    int c = blockIdx.x, t = threadIdx.x;              // blockDim = 512
    if (t < nbkt) cnt[t] = 0;
    int cb = 0;
    if (t < nbkt) {
        int idx = t * nch + c;
        cb = partial[idx >> 8] + incl[idx] - histT[idx];
    }
    __syncthreads();

    int beg = c * CHUNK, end = min(ne, beg + CHUNK);
    int nloc = end - beg;
    bool is32 = (*flag != 0);

    unsigned int rec[8];
    int bk[8];
#pragma unroll
    for (int r = 0; r < 8; ++r) {
        int i = beg + t + r * 512;
        bk[r] = -1;
        if (i < end) {
            int s, d;
            if (is32) {
                s = ((const int*)edges)[i];
                d = ((const int*)edges)[ne + i];
            } else {
                s = (int)((const long long*)edges)[i];
                d = (int)((const long long*)edges)[ne + i];
            }
            rec[r] = ((unsigned int)s << 8) | (unsigned int)(d & (SB - 1));
            bk[r]  = d >> 8;
            atomicAdd(&cnt[bk[r]], 1);
        }
    }
    __syncthreads();

    int v0 = (t < nbkt) ? cnt[t] : 0;
    cursor[t] = v0;
    __syncthreads();
    for (int off = 1; off < 512; off <<= 1) {
        int add = (t >= off) ? cursor[t - off] : 0;
        __syncthreads();
        cursor[t] += add;
        __syncthreads();
    }
    int inc = cursor[t];
    __syncthreads();
    int lb = inc - v0;
    cursor[t] = lb;
    if (t < nbkt) delta[t] = cb - lb;
    __syncthreads();

#pragma unroll
    for (int r = 0; r < 8; ++r) {
        if (bk[r] >= 0) {
            int pos = atomicAdd(&cursor[bk[r]], 1);
            srt[pos] = rec[r];
            bkl[pos] = (unsigned short)bk[r];
        }
    }
    __syncthreads();

    for (int i = t; i < nloc; i += 512)
        ebuf[delta[bkl[i]] + i] = srt[i];
}

// ---------------------------------------------------------------------------
// Phase 2: per-bucket CSR finalize; computes dinv; LDS-staged coalesced
// csr_src write; chunk_base inline.
// ---------------------------------------------------------------------------
__global__ void bucket_finalize(const unsigned int* __restrict__ ebuf,
                                const int* __restrict__ histT, const int* __restrict__ inclG,
                                const int* __restrict__ partial,
                                int* __restrict__ row_ptr, float* __restrict__ dinv,
                                int* __restrict__ csr_src,
                                int n, int e, int nch, int nbkt) {
    __shared__ int deg[SB];
    __shared__ int incl[SB];
    __shared__ int cur[SB];
    __shared__ int stage[4608];                        // 18 KB staging
    __shared__ int sbase, sbend;
    int b = blockIdx.x, t = threadIdx.x;               // blockDim = SB = 256
    int node0 = b * SB;
    int nn = min(SB, n - node0);
    if (t == 0) {
        int i0 = b * nch;
        sbase = partial[i0 >> 8] + inclG[i0] - histT[i0];
        if (b == nbkt - 1) sbend = e;
        else {
            int i1 = (b + 1) * nch;
            sbend = partial[i1 >> 8] + inclG[i1] - histT[i1];
        }
    }
    deg[t] = 0;
    __syncthreads();
    int base = sbase, bend = sbend;

    for (int i = base + t; i < bend; i += SB)
        atomicAdd(&deg[ebuf[i] & (SB - 1)], 1);
    __syncthreads();

    incl[t] = deg[t];
    __syncthreads();
    for (int off = 1; off < SB; off <<= 1) {
        int add = (t >= off) ? incl[t - off] : 0;
        __syncthreads();
        incl[t] += add;
        __syncthreads();
    }
    int lrow = base + incl[t] - deg[t];
    cur[t] = lrow - base;                              // local cursor
    if (t < nn) {
        row_ptr[node0 + t] = lrow;
        dinv[node0 + t]    = rsqrtf((float)(deg[t] + 1));
    }
    if (b == nbkt - 1 && t == 0) row_ptr[n] = e;
    __syncthreads();

    int cntE = bend - base;
    if (cntE <= 4608) {
        for (int i = base + t; i < bend; i += SB) {
            unsigned int r = ebuf[i];
            int pos = atomicAdd(&cur[r & (SB - 1)], 1);
            stage[pos] = (int)(r >> 8);
        }
        __syncthreads();
        for (int i = t; i < cntE; i += SB)             // coalesced linear store
            csr_src[base + i] = stage[i];
    } else {
        for (int i = base + t; i < bend; i += SB) {
            unsigned int r = ebuf[i];
            int pos = atomicAdd(&cur[r & (SB - 1)], 1);
            csr_src[base + pos] = (int)(r >> 8);
        }
    }
}

// ---------------------------------------------------------------------------
// MFMA GEMM (needs dinv, so runs after bucket_finalize): 256 threads.
// ---------------------------------------------------------------------------
template <int NC, bool F32IN>
__launch_bounds__(256)
__global__ void gemm_mfma(const void* __restrict__ Xin,
                          const unsigned short* __restrict__ Wf,
                          const float* __restrict__ dinv,
                          unsigned short* __restrict__ hs, int nrows) {
    constexpr int K = 128;
    __shared__ __align__(16) unsigned short Xl[16 * 128 * 8];   // 32 KB

    const int tid  = threadIdx.x;
    const int row0 = blockIdx.x * 128;

    for (int i = tid; i < 128 * 32; i += 256) {        // stage X tile
        int r  = i >> 5;
        int c4 = i & 31;
        int gr = row0 + r;
        ushort4 v = make_ushort4(0, 0, 0, 0);
        if (gr < nrows) {
            if (F32IN) {
                float4 f = ((const float4*)((const float*)Xin + (size_t)gr * K))[c4];
                v.x = f2bf(f.x); v.y = f2bf(f.y); v.z = f2bf(f.z); v.w = f2bf(f.w);
            } else {
                v = ((const ushort4*)((const unsigned short*)Xin + (size_t)gr * K))[c4];
            }
        }
        int k   = c4 * 4;
        int grp = k >> 3;                              // kt*4 + q
        int j0  = k & 7;                               // 0 or 4
        *(ushort4*)(Xl + ((size_t)grp * 128 + r) * 8 + j0) = v;
    }
    __syncthreads();

    const int wv   = tid >> 6;
    const int lane = tid & 63;
    const int m    = lane & 15;
    const int q    = lane >> 4;

    bf16x8 af[2][4];
#pragma unroll
    for (int h = 0; h < 2; ++h)
#pragma unroll
        for (int kt = 0; kt < 4; ++kt)
            af[h][kt] = *(const bf16x8*)(Xl + (((kt * 4 + q) * 128) + h * 64 + wv * 16 + m) * 8);

    int   rbase[2];
    float dv[2][4];
#pragma unroll
    for (int h = 0; h < 2; ++h) {
        rbase[h] = row0 + h * 64 + wv * 16 + q * 4;
#pragma unroll
        for (int i = 0; i < 4; ++i)
            dv[h][i] = (rbase[h] + i < nrows) ? dinv[rbase[h] + i] : 0.f;
    }

#pragma unroll
    for (int nt = 0; nt < NC / 16; ++nt) {
        bf16x8 bfr[4];
#pragma unroll
        for (int kt = 0; kt < 4; ++kt)
            bfr[kt] = *(const bf16x8*)(Wf + (((size_t)(kt * 4 + q) * NC) + nt * 16 + m) * 8);
#pragma unroll
        for (int h = 0; h < 2; ++h) {
            f32x4 acc = {0.f, 0.f, 0.f, 0.f};
#pragma unroll
            for (int kt = 0; kt < 4; ++kt)
                acc = __builtin_amdgcn_mfma_f32_16x16x32_bf16(af[h][kt], bfr[kt], acc, 0, 0, 0);
#pragma unroll
            for (int i = 0; i < 4; ++i) {
                int g = rbase[h] + i;
                if (g < nrows)
                    hs[(size_t)g * NC + nt * 16 + m] = f2bf(acc[i] * dv[h][i]);
            }
        }
    }
}

// ---------------------------------------------------------------------------
// FUSED layer-1 aggregate + layer-2 GEMM.  hs2 now written SLICE-MAJOR:
// hs2s[slice][node] (uint4 = 8 bf16 feats per slice), enabling the
// XCD-affine sliced layer-2 aggregate.  Values bit-identical.
// ---------------------------------------------------------------------------
__launch_bounds__(256)
__global__ void aggregate_fused_l1(const int* __restrict__ row_ptr,
                                   const int* __restrict__ csr_src,
                                   const uint4* __restrict__ hsu,
                                   const float* __restrict__ dinv,
                                   const float* __restrict__ b,
                                   const unsigned short* __restrict__ Wf2,
                                   unsigned short* __restrict__ hs2, int n) {
    constexpr int TPN = 16;
    constexpr int NPB = 16;
    constexpr int CH  = 16;

    __shared__ __align__(16) unsigned short h1t[16 * 136];   // 272 B/row
    __shared__ float dl[16];
    __shared__ __align__(16) unsigned short outt[16 * 64];   // 2 KB

    const int node0 = blockIdx.x * NPB;
    const int nl    = threadIdx.x / TPN;
    const int t     = threadIdx.x % TPN;
    const int node  = min(node0 + nl, n - 1);
    const int lane  = threadIdx.x & 63;
    const int gb    = lane & ~(TPN - 1);

    uint4 u = hsu[(size_t)node * TPN + t];            // self-loop term
    float a[8];
    a[0] = bflo(u.x); a[1] = bfhi(u.x); a[2] = bflo(u.y); a[3] = bfhi(u.y);
    a[4] = bflo(u.z); a[5] = bfhi(u.z); a[6] = bflo(u.w); a[7] = bfhi(u.w);

    int beg = row_ptr[node], end = row_ptr[node + 1];

    if (beg < end) {
        const u32x4* hb = (const u32x4*)hsu;
        u32x4 v[CH];
        int sva;
        int base = beg;

        {
            const int* pc0 = csr_src + min(base + t, end - 1);
            asm volatile("global_load_dword %0, %1, off" : "=&v"(sva) : "v"(pc0));
        }
        asm volatile("s_waitcnt vmcnt(0)");
        __builtin_amdgcn_sched_barrier(0);

        while (true) {
            int rem = min(CH, end - base);

#pragma unroll
            for (int j = 0; j < CH; ++j) {
                int jj = min(j, rem - 1);
                int sj = __shfl(sva, gb + jj, 64);
                const u32x4* p = hb + (size_t)sj * TPN + t;
                asm volatile("global_load_dwordx4 %0, %1, off" : "=&v"(v[j]) : "v"(p));
            }

            int  nbase = base + CH;
            bool more  = nbase < end;
            if (more) {
                const int* pc0 = csr_src + min(nbase + t, end - 1);
                asm volatile("global_load_dword %0, %1, off" : "=&v"(sva) : "v"(pc0));
                asm volatile("s_waitcnt vmcnt(1)");
            } else {
                asm volatile("s_waitcnt vmcnt(0)");
            }
            __builtin_amdgcn_sched_barrier(0);

#pragma unroll
            for (int j = 0; j < CH; ++j) {
                if (j < rem) {
                    unsigned int x0 = v[j][0], x1 = v[j][1], x2 = v[j][2], x3 = v[j][3];
                    a[0] += bflo(x0); a[1] += bfhi(x0);
                    a[2] += bflo(x1); a[3] += bfhi(x1);
                    a[4] += bflo(x2); a[5] += bfhi(x2);
                    a[6] += bflo(x3); a[7] += bfhi(x3);
                }
            }

            if (!more) break;
            base = nbase;
            asm volatile("s_waitcnt vmcnt(0)");
            __builtin_amdgcn_sched_barrier(0);
        }
    }

    float dvn = dinv[node];
    float4 b0 = ((const float4*)b)[2 * t];
    float4 b1 = ((const float4*)b)[2 * t + 1];
    float o[8];
    o[0] = a[0] * dvn + b0.x; o[1] = a[1] * dvn + b0.y;
    o[2] = a[2] * dvn + b0.z; o[3] = a[3] * dvn + b0.w;
    o[4] = a[4] * dvn + b1.x; o[5] = a[5] * dvn + b1.y;
    o[6] = a[6] * dvn + b1.z; o[7] = a[7] * dvn + b1.w;
#pragma unroll
    for (int j = 0; j < 8; ++j) o[j] = fmaxf(o[j], 0.f);

    uint4 ov;
    ov.x = (unsigned int)f2bf(o[0]) | ((unsigned int)f2bf(o[1]) << 16);
    ov.y = (unsigned int)f2bf(o[2]) | ((unsigned int)f2bf(o[3]) << 16);
    ov.z = (unsigned int)f2bf(o[4]) | ((unsigned int)f2bf(o[5]) << 16);
    ov.w = (unsigned int)f2bf(o[6]) | ((unsigned int)f2bf(o[7]) << 16);
    *(uint4*)((char*)h1t + (size_t)nl * 272 + t * 16) = ov;
    if (t == 0) dl[nl] = dvn;
    __syncthreads();

    {
        const int wv = threadIdx.x >> 6;
        const int m  = lane & 15;
        const int q  = lane >> 4;

        f32x4 acc = {0.f, 0.f, 0.f, 0.f};
#pragma unroll
        for (int kt = 0; kt < 4; ++kt) {
            bf16x8 af  = *(const bf16x8*)((const char*)h1t + (size_t)m * 272 + q * 16 + kt * 64);
            bf16x8 bfr = *(const bf16x8*)(Wf2 + (((size_t)(kt * 4 + q) * 64) + wv * 16 + m) * 8);
            acc = __builtin_amdgcn_mfma_f32_16x16x32_bf16(af, bfr, acc, 0, 0, 0);
        }
#pragma unroll
        for (int i = 0; i < 4; ++i) {
            int nd = q * 4 + i;
            outt[nd * 64 + wv * 16 + m] = f2bf(acc[i] * dl[nd]);
        }
    }
    __syncthreads();

    {   // slice-major store: hs2s[slice][node] (uint4), 256B runs per slice
        int i = threadIdx.x;
        if (i < 128) {
            int sl = i >> 4;                           // slice 0..7
            int ln = i & 15;                           // local node
            int gnode = node0 + ln;
            if (gnode < n)
                ((uint4*)hs2)[(size_t)sl * n + gnode] = ((const uint4*)outt)[ln * 8 + sl];
        }
    }
}

// ---------------------------------------------------------------------------
// Layer-2 aggregate, SLICE-PARTITIONED: one lane per (node, slice-of-8-feats).
// slice = blockIdx & 7 rides the XCD round-robin, so each XCD's random
// gathers stay inside its own 1.6 MB L2-resident slice (L2-hit path instead
// of the 3.15 TB/s miss path).  Same ascending-edge f32 accumulation order
// per feature as before -> bit-identical output.
// ---------------------------------------------------------------------------
__launch_bounds__(256)
__global__ void aggregate_l2_sliced(const int* __restrict__ row_ptr,
                                    const int* __restrict__ csr_src,
                                    const uint4* __restrict__ hs2s,   // [8][n]
                                    const float* __restrict__ dinv,
                                    const float* __restrict__ b,
                                    float* __restrict__ out, int n) {
    const int slice = blockIdx.x & 7;
    const int node  = (blockIdx.x >> 3) * 256 + threadIdx.x;
    if (node >= n) return;

    const u32x4* hb = (const u32x4*)(hs2s + (size_t)slice * n);

    u32x4 u = hb[node];                                // self-loop term
    float a[8];
    a[0] = bflo(u[0]); a[1] = bfhi(u[0]); a[2] = bflo(u[1]); a[3] = bfhi(u[1]);
    a[4] = bflo(u[2]); a[5] = bfhi(u[2]); a[6] = bflo(u[3]); a[7] = bfhi(u[3]);

    int beg = row_ptr[node], end = row_ptr[node + 1];

    if (beg < end) {
        u32x4 v[8];
        int s[8];                                      // static-indexed only
        int base = beg;

#pragma unroll
        for (int j = 0; j < 8; ++j) {                  // prologue csr loads
            const int* pc = csr_src + min(base + j, end - 1);
            asm volatile("global_load_dword %0, %1, off" : "=&v"(s[j]) : "v"(pc));
        }
        asm volatile("s_waitcnt vmcnt(0)");
        __builtin_amdgcn_sched_barrier(0);

        while (true) {
            int rem = end - base;                      // >= 1

#pragma unroll
            for (int j = 0; j < 8; ++j) {              // 8 gathers in flight
                const u32x4* p = hb + s[j];
                asm volatile("global_load_dwordx4 %0, %1, off" : "=&v"(v[j]) : "v"(p));
            }

            int  nbase = base + 8;
            bool more  = nbase < end;
            if (more) {                                // next csr batch now
#pragma unroll
                for (int j = 0; j < 8; ++j) {
                    const int* pc = csr_src + min(nbase + j, end - 1);
                    asm volatile("global_load_dword %0, %1, off" : "=&v"(s[j]) : "v"(pc));
                }
                asm volatile("s_waitcnt vmcnt(8)");    // gathers done, csr in flight
            } else {
                asm volatile("s_waitcnt vmcnt(0)");
            }
            __builtin_amdgcn_sched_barrier(0);

#pragma unroll
            for (int j = 0; j < 8; ++j) {
                if (j < rem) {
                    a[0] += bflo(v[j][0]); a[1] += bfhi(v[j][0]);
                    a[2] += bflo(v[j][1]); a[3] += bfhi(v[j][1]);
                    a[4] += bflo(v[j][2]); a[5] += bfhi(v[j][2]);
                    a[6] += bflo(v[j][3]); a[7] += bfhi(v[j][3]);
                }
            }

            if (!more) break;
            base = nbase;
            asm volatile("s_waitcnt vmcnt(0)");
            __builtin_amdgcn_sched_barrier(0);
        }
    }

    float dvn = dinv[node];
    float4 b0 = ((const float4*)b)[2 * slice];
    float4 b1 = ((const float4*)b)[2 * slice + 1];
    float o[8];
    o[0] = a[0] * dvn + b0.x; o[1] = a[1] * dvn + b0.y;
    o[2] = a[2] * dvn + b0.z; o[3] = a[3] * dvn + b0.w;
    o[4] = a[4] * dvn + b1.x; o[5] = a[5] * dvn + b1.y;
    o[6] = a[6] * dvn + b1.z; o[7] = a[7] * dvn + b1.w;

    float4* op = (float4*)out + (size_t)node * (NOUT / 4) + 2 * slice;
    op[0] = make_float4(o[0], o[1], o[2], o[3]);
    op[1] = make_float4(o[4], o[5], o[6], o[7]);
}

// ---------------------------------------------------------------------------
extern "C" void kernel_launch(void* const* d_in, const int* in_sizes, int n_in,
                              void* d_out, int out_size, void* d_ws, size_t ws_size,
                              hipStream_t stream) {
    const void*  edge = d_in[0];
    const float* x    = (const float*)d_in[1];
    const float* W1   = (const float*)d_in[2];
    const float* b1   = (const float*)d_in[3];
    const float* W2   = (const float*)d_in[4];
    const float* b2   = (const float*)d_in[5];
    float* out = (float*)d_out;

    const int E    = in_sizes[0] / 2;
    const int N    = in_sizes[1] / NFEATS;
    const int NBKT = (N + SB - 1) / SB;        // 391
    const int NCH  = (E + CHUNK - 1) / CHUNK;  // 391
    const int M    = NBKT * NCH;

    char* w = (char*)d_ws;
    auto carve = [&](size_t bytes) { void* p = w; w += (bytes + 255) & ~(size_t)255; return p; };
    int*            flag       = (int*)           carve(256);
    int*            histT      = (int*)           carve(sizeof(int) * (size_t)M);
    int*            incl       = (int*)           carve(sizeof(int) * (size_t)M);
    int*            partial    = (int*)           carve(sizeof(int) * 4096);
    int*            row_ptr    = (int*)           carve(sizeof(int) * ((size_t)N + 1));
    float*          dinv       = (float*)         carve(sizeof(float) * (size_t)N);
    unsigned int*   ebuf       = (unsigned int*)  carve(sizeof(int) * (size_t)E);
    int*            csr_src    = (int*)           carve(sizeof(int) * (size_t)E);
    unsigned short* Wf1        = (unsigned short*)carve(2 * (size_t)NFEATS * NHIDS);
    unsigned short* Wf2        = (unsigned short*)carve(2 * (size_t)NHIDS * NOUT);
    unsigned short* hs1        = (unsigned short*)carve(2 * (size_t)N * NHIDS);
    unsigned short* hs2        = (unsigned short*)carve(2 * (size_t)N * NOUT);

    const int nbS = (M + 255) / 256;

    // 1. detect + weight pack (fused)
    detect_wpack<<<65, 256, 0, stream>>>(edge, flag, (long long)N, W1, Wf1, W2, Wf2);

    // 2-5. CSR build
    hist_kernel<<<NCH, 512, 0, stream>>>(edge, flag, histT, E, NCH, NBKT);
    scan_block<<<nbS, 256, 0, stream>>>(histT, incl, partial, M);
    scan_partials<<<1, 512, 0, stream>>>(partial, nbS);
    scatter_chunks<<<NCH, 512, 0, stream>>>(edge, flag, histT, incl, partial,
                                            ebuf, E, NCH, NBKT);
    bucket_finalize<<<NBKT, SB, 0, stream>>>(ebuf, histT, incl, partial,
                                             row_ptr, dinv, csr_src, N, E, NCH, NBKT);

    // 6. layer-1 GEMM (needs dinv)
    gemm_mfma<NHIDS, true><<<(N + 127) / 128, 256, 0, stream>>>(x, Wf1, dinv, hs1, N);

    // 7. fused: layer-1 aggregate + ReLU + layer-2 GEMM -> hs2 (slice-major)
    aggregate_fused_l1<<<(N + 15) / 16, 256, 0, stream>>>(
        row_ptr, csr_src, (const uint4*)hs1, dinv, b1, Wf2, hs2, N);

    // 8. layer-2 aggregate, slice-partitioned (XCD-affine) -> out
    {
        int nblk = ((N + 255) / 256) * 8;
        aggregate_l2_sliced<<<nblk, 256, 0, stream>>>(
            row_ptr, csr_src, (const uint4*)hs2, dinv, b2, out, N);
    }
}

// Round 8
// 247.151 us; speedup vs baseline: 1.2062x; 1.1740x over previous
//
#include <hip/hip_runtime.h>
#include <cstdint>
#include <cstddef>

#define NFEATS 128
#define NHIDS  128
#define NOUT   64
#define SB     256    // nodes per bucket (dst >> 8)
#define CHUNK  4096   // edges per chunk in the radix partition

using bf16x8 = __attribute__((ext_vector_type(8))) short;
using f32x4  = __attribute__((ext_vector_type(4))) float;
using u32x4  = __attribute__((ext_vector_type(4))) unsigned int;

__device__ inline unsigned short f2bf(float f) {           // round-to-nearest-even
    union { float f; unsigned int u; } v; v.f = f;
    unsigned int r = (v.u + 0x7FFFu + ((v.u >> 16) & 1u)) >> 16;
    return (unsigned short)r;
}
__device__ inline float bflo(unsigned int u) { return __uint_as_float(u << 16); }
__device__ inline float bfhi(unsigned int u) { return __uint_as_float(u & 0xFFFF0000u); }

// ---------------------------------------------------------------------------
// Launch 1: edge dtype detect (block 0) + weight pack (blocks 1..64).
// ---------------------------------------------------------------------------
__global__ void detect_wpack(const void* __restrict__ p, int* __restrict__ flag,
                             long long n_nodes,
                             const float* __restrict__ W1, unsigned short* __restrict__ Wf1,
                             const float* __restrict__ W2, unsigned short* __restrict__ Wf2) {
    if (blockIdx.x == 0) {
        if (threadIdx.x < 64) {
            const long long* q = (const long long*)p;
            long long v = q[threadIdx.x];
            int bad = (v < 0 || v >= n_nodes) ? 1 : 0;
            unsigned long long m = __ballot(bad);
            if (threadIdx.x == 0) *flag = (m != 0ULL) ? 1 : 0;
        }
        return;
    }
    int i = (blockIdx.x - 1) * 256 + threadIdx.x;      // [0, 16384)
    if (i < 128 * 128) {                               // W1: [128][128]
        int k = i >> 7, n2 = i & 127;
        Wf1[(((k >> 3) * 128) + n2) * 8 + (k & 7)] = f2bf(W1[i]);
    }
    if (i < 128 * 64) {                                // W2: [128][64]
        int k = i >> 6, n2 = i & 63;
        Wf2[(((k >> 3) * 64) + n2) * 8 + (k & 7)] = f2bf(W2[i]);
    }
}

// ---------------------------------------------------------------------------
// Phase 1a: per-(chunk,bucket) histogram. histT[b*nch + c].
// ---------------------------------------------------------------------------
__global__ __launch_bounds__(512)
void hist_kernel(const void* __restrict__ edges, const int* __restrict__ flag,
                 int* __restrict__ histT, int ne, int nch, int nbkt) {
    __shared__ int h[1024];
    int c = blockIdx.x, t = threadIdx.x;              // blockDim = 512
    for (int i = t; i < nbkt; i += 512) h[i] = 0;
    __syncthreads();
    int beg = c * CHUNK, end = min(ne, beg + CHUNK);
    bool is32 = (*flag != 0);
    for (int i = beg + t; i < end; i += 512) {
        int d = is32 ? ((const int*)edges)[ne + i]
                     : (int)((const long long*)edges)[ne + i];
        atomicAdd(&h[d >> 8], 1);
    }
    __syncthreads();
    for (int i = t; i < nbkt; i += 512)
        histT[i * nch + c] = h[i];
}

// ---------------------------------------------------------------------------
// Exclusive scan over histT.  chunk_base computed inline by consumers:
// CB(i) = partial[i>>8] + incl[i] - histT[i].
// ---------------------------------------------------------------------------
__global__ void scan_block(const int* __restrict__ v, int* __restrict__ incl,
                           int* __restrict__ partial, int n) {
    __shared__ int sh[256];
    int t = threadIdx.x;
    int i = blockIdx.x * 256 + t;
    sh[t] = (i < n) ? v[i] : 0;
    __syncthreads();
    for (int off = 1; off < 256; off <<= 1) {
        int add = (t >= off) ? sh[t - off] : 0;
        __syncthreads();
        sh[t] += add;
        __syncthreads();
    }
    if (i < n) incl[i] = sh[t];
    if (t == 255) partial[blockIdx.x] = sh[255];
}

__global__ void scan_partials(int* partial, int nb) {
    __shared__ int sh[512];
    __shared__ int carry;
    int t = threadIdx.x;
    if (t == 0) carry = 0;
    __syncthreads();
    for (int base = 0; base < nb; base += 512) {
        int idx = base + t;
        sh[t] = (idx < nb) ? partial[idx] : 0;
        __syncthreads();
        for (int off = 1; off < 512; off <<= 1) {
            int add = (t >= off) ? sh[t - off] : 0;
            __syncthreads();
            sh[t] += add;
            __syncthreads();
        }
        int excl = carry + ((t == 0) ? 0 : sh[t - 1]);
        if (idx < nb) partial[idx] = excl;
        __syncthreads();
        if (t == 0) carry += sh[511];
        __syncthreads();
    }
}

// ---------------------------------------------------------------------------
// Phase 1b: LDS bucket sort + coalesced writes (chunk_base inline).
// ---------------------------------------------------------------------------
__global__ __launch_bounds__(512)
void scatter_chunks(const void* __restrict__ edges, const int* __restrict__ flag,
                    const int* __restrict__ histT, const int* __restrict__ incl,
                    const int* __restrict__ partial,
                    unsigned int* __restrict__ ebuf,
                    int ne, int nch, int nbkt) {
    __shared__ int cnt[512];
    __shared__ int cursor[512];
    __shared__ int delta[512];
    __shared__ unsigned int   srt[CHUNK];            // 16 KB
    __shared__ unsigned short bkl[CHUNK];            // 8 KB
    int c = blockIdx.x, t = threadIdx.x;              // blockDim = 512
    if (t < nbkt) cnt[t] = 0;
    int cb = 0;
    if (t < nbkt) {
        int idx = t * nch + c;
        cb = partial[idx >> 8] + incl[idx] - histT[idx];
    }
    __syncthreads();

    int beg = c * CHUNK, end = min(ne, beg + CHUNK);
    int nloc = end - beg;
    bool is32 = (*flag != 0);

    unsigned int rec[8];
    int bk[8];
#pragma unroll
    for (int r = 0; r < 8; ++r) {
        int i = beg + t + r * 512;
        bk[r] = -1;
        if (i < end) {
            int s, d;
            if (is32) {
                s = ((const int*)edges)[i];
                d = ((const int*)edges)[ne + i];
            } else {
                s = (int)((const long long*)edges)[i];
                d = (int)((const long long*)edges)[ne + i];
            }
            rec[r] = ((unsigned int)s << 8) | (unsigned int)(d & (SB - 1));
            bk[r]  = d >> 8;
            atomicAdd(&cnt[bk[r]], 1);
        }
    }
    __syncthreads();

    int v0 = (t < nbkt) ? cnt[t] : 0;
    cursor[t] = v0;
    __syncthreads();
    for (int off = 1; off < 512; off <<= 1) {
        int add = (t >= off) ? cursor[t - off] : 0;
        __syncthreads();
        cursor[t] += add;
        __syncthreads();
    }
    int inc = cursor[t];
    __syncthreads();
    int lb = inc - v0;
    cursor[t] = lb;
    if (t < nbkt) delta[t] = cb - lb;
    __syncthreads();

#pragma unroll
    for (int r = 0; r < 8; ++r) {
        if (bk[r] >= 0) {
            int pos = atomicAdd(&cursor[bk[r]], 1);
            srt[pos] = rec[r];
            bkl[pos] = (unsigned short)bk[r];
        }
    }
    __syncthreads();

    for (int i = t; i < nloc; i += 512)
        ebuf[delta[bkl[i]] + i] = srt[i];
}

// ---------------------------------------------------------------------------
// Phase 2: per-bucket CSR finalize; computes dinv; LDS-staged coalesced
// csr_src write; chunk_base inline.
// ---------------------------------------------------------------------------
__global__ void bucket_finalize(const unsigned int* __restrict__ ebuf,
                                const int* __restrict__ histT, const int* __restrict__ inclG,
                                const int* __restrict__ partial,
                                int* __restrict__ row_ptr, float* __restrict__ dinv,
                                int* __restrict__ csr_src,
                                int n, int e, int nch, int nbkt) {
    __shared__ int deg[SB];
    __shared__ int incl[SB];
    __shared__ int cur[SB];
    __shared__ int stage[4608];                        // 18 KB staging
    __shared__ int sbase, sbend;
    int b = blockIdx.x, t = threadIdx.x;               // blockDim = SB = 256
    int node0 = b * SB;
    int nn = min(SB, n - node0);
    if (t == 0) {
        int i0 = b * nch;
        sbase = partial[i0 >> 8] + inclG[i0] - histT[i0];
        if (b == nbkt - 1) sbend = e;
        else {
            int i1 = (b + 1) * nch;
            sbend = partial[i1 >> 8] + inclG[i1] - histT[i1];
        }
    }
    deg[t] = 0;
    __syncthreads();
    int base = sbase, bend = sbend;

    for (int i = base + t; i < bend; i += SB)
        atomicAdd(&deg[ebuf[i] & (SB - 1)], 1);
    __syncthreads();

    incl[t] = deg[t];
    __syncthreads();
    for (int off = 1; off < SB; off <<= 1) {
        int add = (t >= off) ? incl[t - off] : 0;
        __syncthreads();
        incl[t] += add;
        __syncthreads();
    }
    int lrow = base + incl[t] - deg[t];
    cur[t] = lrow - base;                              // local cursor
    if (t < nn) {
        row_ptr[node0 + t] = lrow;
        dinv[node0 + t]    = rsqrtf((float)(deg[t] + 1));
    }
    if (b == nbkt - 1 && t == 0) row_ptr[n] = e;
    __syncthreads();

    int cntE = bend - base;
    if (cntE <= 4608) {
        for (int i = base + t; i < bend; i += SB) {
            unsigned int r = ebuf[i];
            int pos = atomicAdd(&cur[r & (SB - 1)], 1);
            stage[pos] = (int)(r >> 8);
        }
        __syncthreads();
        for (int i = t; i < cntE; i += SB)             // coalesced linear store
            csr_src[base + i] = stage[i];
    } else {
        for (int i = base + t; i < bend; i += SB) {
            unsigned int r = ebuf[i];
            int pos = atomicAdd(&cur[r & (SB - 1)], 1);
            csr_src[base + pos] = (int)(r >> 8);
        }
    }
}

// ---------------------------------------------------------------------------
// MFMA GEMM (needs dinv, so runs after bucket_finalize): 256 threads.
// ---------------------------------------------------------------------------
template <int NC, bool F32IN>
__launch_bounds__(256)
__global__ void gemm_mfma(const void* __restrict__ Xin,
                          const unsigned short* __restrict__ Wf,
                          const float* __restrict__ dinv,
                          unsigned short* __restrict__ hs, int nrows) {
    constexpr int K = 128;
    __shared__ __align__(16) unsigned short Xl[16 * 128 * 8];   // 32 KB

    const int tid  = threadIdx.x;
    const int row0 = blockIdx.x * 128;

    for (int i = tid; i < 128 * 32; i += 256) {        // stage X tile
        int r  = i >> 5;
        int c4 = i & 31;
        int gr = row0 + r;
        ushort4 v = make_ushort4(0, 0, 0, 0);
        if (gr < nrows) {
            if (F32IN) {
                float4 f = ((const float4*)((const float*)Xin + (size_t)gr * K))[c4];
                v.x = f2bf(f.x); v.y = f2bf(f.y); v.z = f2bf(f.z); v.w = f2bf(f.w);
            } else {
                v = ((const ushort4*)((const unsigned short*)Xin + (size_t)gr * K))[c4];
            }
        }
        int k   = c4 * 4;
        int grp = k >> 3;                              // kt*4 + q
        int j0  = k & 7;                               // 0 or 4
        *(ushort4*)(Xl + ((size_t)grp * 128 + r) * 8 + j0) = v;
    }
    __syncthreads();

    const int wv   = tid >> 6;
    const int lane = tid & 63;
    const int m    = lane & 15;
    const int q    = lane >> 4;

    bf16x8 af[2][4];
#pragma unroll
    for (int h = 0; h < 2; ++h)
#pragma unroll
        for (int kt = 0; kt < 4; ++kt)
            af[h][kt] = *(const bf16x8*)(Xl + (((kt * 4 + q) * 128) + h * 64 + wv * 16 + m) * 8);

    int   rbase[2];
    float dv[2][4];
#pragma unroll
    for (int h = 0; h < 2; ++h) {
        rbase[h] = row0 + h * 64 + wv * 16 + q * 4;
#pragma unroll
        for (int i = 0; i < 4; ++i)
            dv[h][i] = (rbase[h] + i < nrows) ? dinv[rbase[h] + i] : 0.f;
    }

#pragma unroll
    for (int nt = 0; nt < NC / 16; ++nt) {
        bf16x8 bfr[4];
#pragma unroll
        for (int kt = 0; kt < 4; ++kt)
            bfr[kt] = *(const bf16x8*)(Wf + (((size_t)(kt * 4 + q) * NC) + nt * 16 + m) * 8);
#pragma unroll
        for (int h = 0; h < 2; ++h) {
            f32x4 acc = {0.f, 0.f, 0.f, 0.f};
#pragma unroll
            for (int kt = 0; kt < 4; ++kt)
                acc = __builtin_amdgcn_mfma_f32_16x16x32_bf16(af[h][kt], bfr[kt], acc, 0, 0, 0);
#pragma unroll
            for (int i = 0; i < 4; ++i) {
                int g = rbase[h] + i;
                if (g < nrows)
                    hs[(size_t)g * NC + nt * 16 + m] = f2bf(acc[i] * dv[h][i]);
            }
        }
    }
}

// ---------------------------------------------------------------------------
// FUSED layer-1 aggregate + layer-2 GEMM (at the random-gather fetch-path
// floor: 186 MB FETCH at ~3.15 TB/s).
// ---------------------------------------------------------------------------
__launch_bounds__(256)
__global__ void aggregate_fused_l1(const int* __restrict__ row_ptr,
                                   const int* __restrict__ csr_src,
                                   const uint4* __restrict__ hsu,
                                   const float* __restrict__ dinv,
                                   const float* __restrict__ b,
                                   const unsigned short* __restrict__ Wf2,
                                   unsigned short* __restrict__ hs2, int n) {
    constexpr int TPN = 16;
    constexpr int NPB = 16;
    constexpr int CH  = 16;

    __shared__ __align__(16) unsigned short h1t[16 * 136];   // 272 B/row
    __shared__ float dl[16];
    __shared__ __align__(16) unsigned short outt[16 * 64];   // 2 KB

    const int node0 = blockIdx.x * NPB;
    const int nl    = threadIdx.x / TPN;
    const int t     = threadIdx.x % TPN;
    const int node  = min(node0 + nl, n - 1);
    const int lane  = threadIdx.x & 63;
    const int gb    = lane & ~(TPN - 1);

    uint4 u = hsu[(size_t)node * TPN + t];            // self-loop term
    float a[8];
    a[0] = bflo(u.x); a[1] = bfhi(u.x); a[2] = bflo(u.y); a[3] = bfhi(u.y);
    a[4] = bflo(u.z); a[5] = bfhi(u.z); a[6] = bflo(u.w); a[7] = bfhi(u.w);

    int beg = row_ptr[node], end = row_ptr[node + 1];

    if (beg < end) {
        const u32x4* hb = (const u32x4*)hsu;
        u32x4 v[CH];
        int sva;
        int base = beg;

        {
            const int* pc0 = csr_src + min(base + t, end - 1);
            asm volatile("global_load_dword %0, %1, off" : "=&v"(sva) : "v"(pc0));
        }
        asm volatile("s_waitcnt vmcnt(0)");
        __builtin_amdgcn_sched_barrier(0);

        while (true) {
            int rem = min(CH, end - base);

#pragma unroll
            for (int j = 0; j < CH; ++j) {
                int jj = min(j, rem - 1);
                int sj = __shfl(sva, gb + jj, 64);
                const u32x4* p = hb + (size_t)sj * TPN + t;
                asm volatile("global_load_dwordx4 %0, %1, off" : "=&v"(v[j]) : "v"(p));
            }

            int  nbase = base + CH;
            bool more  = nbase < end;
            if (more) {
                const int* pc0 = csr_src + min(nbase + t, end - 1);
                asm volatile("global_load_dword %0, %1, off" : "=&v"(sva) : "v"(pc0));
                asm volatile("s_waitcnt vmcnt(1)");
            } else {
                asm volatile("s_waitcnt vmcnt(0)");
            }
            __builtin_amdgcn_sched_barrier(0);

#pragma unroll
            for (int j = 0; j < CH; ++j) {
                if (j < rem) {
                    unsigned int x0 = v[j][0], x1 = v[j][1], x2 = v[j][2], x3 = v[j][3];
                    a[0] += bflo(x0); a[1] += bfhi(x0);
                    a[2] += bflo(x1); a[3] += bfhi(x1);
                    a[4] += bflo(x2); a[5] += bfhi(x2);
                    a[6] += bflo(x3); a[7] += bfhi(x3);
                }
            }

            if (!more) break;
            base = nbase;
            asm volatile("s_waitcnt vmcnt(0)");
            __builtin_amdgcn_sched_barrier(0);
        }
    }

    float dvn = dinv[node];
    float4 b0 = ((const float4*)b)[2 * t];
    float4 b1 = ((const float4*)b)[2 * t + 1];
    float o[8];
    o[0] = a[0] * dvn + b0.x; o[1] = a[1] * dvn + b0.y;
    o[2] = a[2] * dvn + b0.z; o[3] = a[3] * dvn + b0.w;
    o[4] = a[4] * dvn + b1.x; o[5] = a[5] * dvn + b1.y;
    o[6] = a[6] * dvn + b1.z; o[7] = a[7] * dvn + b1.w;
#pragma unroll
    for (int j = 0; j < 8; ++j) o[j] = fmaxf(o[j], 0.f);

    uint4 ov;
    ov.x = (unsigned int)f2bf(o[0]) | ((unsigned int)f2bf(o[1]) << 16);
    ov.y = (unsigned int)f2bf(o[2]) | ((unsigned int)f2bf(o[3]) << 16);
    ov.z = (unsigned int)f2bf(o[4]) | ((unsigned int)f2bf(o[5]) << 16);
    ov.w = (unsigned int)f2bf(o[6]) | ((unsigned int)f2bf(o[7]) << 16);
    *(uint4*)((char*)h1t + (size_t)nl * 272 + t * 16) = ov;
    if (t == 0) dl[nl] = dvn;
    __syncthreads();

    {
        const int wv = threadIdx.x >> 6;
        const int m  = lane & 15;
        const int q  = lane >> 4;

        f32x4 acc = {0.f, 0.f, 0.f, 0.f};
#pragma unroll
        for (int kt = 0; kt < 4; ++kt) {
            bf16x8 af  = *(const bf16x8*)((const char*)h1t + (size_t)m * 272 + q * 16 + kt * 64);
            bf16x8 bfr = *(const bf16x8*)(Wf2 + (((size_t)(kt * 4 + q) * 64) + wv * 16 + m) * 8);
            acc = __builtin_amdgcn_mfma_f32_16x16x32_bf16(af, bfr, acc, 0, 0, 0);
        }
#pragma unroll
        for (int i = 0; i < 4; ++i) {
            int nd = q * 4 + i;
            outt[nd * 64 + wv * 16 + m] = f2bf(acc[i] * dl[nd]);
        }
    }
    __syncthreads();

    {
        int i = threadIdx.x;
        if (i < 128) {
            int gnode = node0 + (i >> 3);
            if (gnode < n)
                ((uint4*)hs2)[(size_t)gnode * 8 + (i & 7)] = ((const uint4*)outt)[i];
        }
    }
}

// ---------------------------------------------------------------------------
// Layer-2 aggregate (F=64), 16-deep asm gather pipeline.  TPN=8 lanes per
// node: 8 lanes x 16 B = 128 B contiguous per edge = 2 cache lines (the
// wave-coalescing operating point R7's slicing experiment proved essential).
// ---------------------------------------------------------------------------
template <int F, bool RELU, bool OUTBF>
__launch_bounds__(256)
__global__ void aggregate_bf16(const int* __restrict__ row_ptr,
                               const int* __restrict__ csr_src,
                               const uint4* __restrict__ hsu,
                               const float* __restrict__ dinv,
                               const float* __restrict__ b,
                               void* __restrict__ out, int n) {
    constexpr int TPN  = F / 8;
    constexpr int NPB  = 256 / TPN;
    constexpr int CH   = 16;
    constexpr int NCSR = CH / TPN;
    int node = blockIdx.x * NPB + threadIdx.x / TPN;
    int t    = threadIdx.x % TPN;
    if (node >= n) return;
    const int lane = threadIdx.x & 63;
    const int gb   = lane & ~(TPN - 1);

    uint4 u = hsu[(size_t)node * TPN + t];
    float a[8];
    a[0] = bflo(u.x); a[1] = bfhi(u.x); a[2] = bflo(u.y); a[3] = bfhi(u.y);
    a[4] = bflo(u.z); a[5] = bfhi(u.z); a[6] = bflo(u.w); a[7] = bfhi(u.w);

    int beg = row_ptr[node], end = row_ptr[node + 1];

    if (beg < end) {
        const u32x4* hb = (const u32x4*)hsu;
        u32x4 v[CH];
        int sva, svb;
        int base = beg;

        {
            const int* pc0 = csr_src + min(base + t, end - 1);
            asm volatile("global_load_dword %0, %1, off" : "=&v"(sva) : "v"(pc0));
            if (NCSR == 2) {
                const int* pc1 = csr_src + min(base + TPN + t, end - 1);
                asm volatile("global_load_dword %0, %1, off" : "=&v"(svb) : "v"(pc1));
            }
        }
        asm volatile("s_waitcnt vmcnt(0)");
        __builtin_amdgcn_sched_barrier(0);

        while (true) {
            int rem = min(CH, end - base);

#pragma unroll
            for (int j = 0; j < CH; ++j) {
                int jj = min(j, rem - 1);
                int sj;
                if (TPN == 16) {
                    sj = __shfl(sva, gb + jj, 64);
                } else {
                    int s0 = __shfl(sva, gb + (jj & 7), 64);
                    int s1 = __shfl(svb, gb + (jj & 7), 64);
                    sj = (jj < 8) ? s0 : s1;
                }
                const u32x4* p = hb + (size_t)sj * TPN + t;
                asm volatile("global_load_dwordx4 %0, %1, off" : "=&v"(v[j]) : "v"(p));
            }

            int  nbase = base + CH;
            bool more  = nbase < end;
            if (more) {
                const int* pc0 = csr_src + min(nbase + t, end - 1);
                asm volatile("global_load_dword %0, %1, off" : "=&v"(sva) : "v"(pc0));
                if (NCSR == 2) {
                    const int* pc1 = csr_src + min(nbase + TPN + t, end - 1);
                    asm volatile("global_load_dword %0, %1, off" : "=&v"(svb) : "v"(pc1));
                }
                if (NCSR == 1) asm volatile("s_waitcnt vmcnt(1)");
                else           asm volatile("s_waitcnt vmcnt(2)");
            } else {
                asm volatile("s_waitcnt vmcnt(0)");
            }
            __builtin_amdgcn_sched_barrier(0);

#pragma unroll
            for (int j = 0; j < CH; ++j) {
                if (j < rem) {
                    unsigned int x0 = v[j][0], x1 = v[j][1], x2 = v[j][2], x3 = v[j][3];
                    a[0] += bflo(x0); a[1] += bfhi(x0);
                    a[2] += bflo(x1); a[3] += bfhi(x1);
                    a[4] += bflo(x2); a[5] += bfhi(x2);
                    a[6] += bflo(x3); a[7] += bfhi(x3);
                }
            }

            if (!more) break;
            base = nbase;
            asm volatile("s_waitcnt vmcnt(0)");
            __builtin_amdgcn_sched_barrier(0);
        }
    }

    float dvn = dinv[node];
    float4 b0 = ((const float4*)b)[2 * t];
    float4 b1 = ((const float4*)b)[2 * t + 1];
    float o[8];
    o[0] = a[0] * dvn + b0.x; o[1] = a[1] * dvn + b0.y;
    o[2] = a[2] * dvn + b0.z; o[3] = a[3] * dvn + b0.w;
    o[4] = a[4] * dvn + b1.x; o[5] = a[5] * dvn + b1.y;
    o[6] = a[6] * dvn + b1.z; o[7] = a[7] * dvn + b1.w;
    if (RELU) {
#pragma unroll
        for (int j = 0; j < 8; ++j) o[j] = fmaxf(o[j], 0.f);
    }
    if (OUTBF) {
        uint4 ov;
        ov.x = (unsigned int)f2bf(o[0]) | ((unsigned int)f2bf(o[1]) << 16);
        ov.y = (unsigned int)f2bf(o[2]) | ((unsigned int)f2bf(o[3]) << 16);
        ov.z = (unsigned int)f2bf(o[4]) | ((unsigned int)f2bf(o[5]) << 16);
        ov.w = (unsigned int)f2bf(o[6]) | ((unsigned int)f2bf(o[7]) << 16);
        ((uint4*)out)[(size_t)node * TPN + t] = ov;
    } else {
        float4* op = (float4*)out + (size_t)node * (F / 4) + 2 * t;
        op[0] = make_float4(o[0], o[1], o[2], o[3]);
        op[1] = make_float4(o[4], o[5], o[6], o[7]);
    }
}

// ---------------------------------------------------------------------------
extern "C" void kernel_launch(void* const* d_in, const int* in_sizes, int n_in,
                              void* d_out, int out_size, void* d_ws, size_t ws_size,
                              hipStream_t stream) {
    const void*  edge = d_in[0];
    const float* x    = (const float*)d_in[1];
    const float* W1   = (const float*)d_in[2];
    const float* b1   = (const float*)d_in[3];
    const float* W2   = (const float*)d_in[4];
    const float* b2   = (const float*)d_in[5];
    float* out = (float*)d_out;

    const int E    = in_sizes[0] / 2;
    const int N    = in_sizes[1] / NFEATS;
    const int NBKT = (N + SB - 1) / SB;        // 391
    const int NCH  = (E + CHUNK - 1) / CHUNK;  // 391
    const int M    = NBKT * NCH;

    char* w = (char*)d_ws;
    auto carve = [&](size_t bytes) { void* p = w; w += (bytes + 255) & ~(size_t)255; return p; };
    int*            flag       = (int*)           carve(256);
    int*            histT      = (int*)           carve(sizeof(int) * (size_t)M);
    int*            incl       = (int*)           carve(sizeof(int) * (size_t)M);
    int*            partial    = (int*)           carve(sizeof(int) * 4096);
    int*            row_ptr    = (int*)           carve(sizeof(int) * ((size_t)N + 1));
    float*          dinv       = (float*)         carve(sizeof(float) * (size_t)N);
    unsigned int*   ebuf       = (unsigned int*)  carve(sizeof(int) * (size_t)E);
    int*            csr_src    = (int*)           carve(sizeof(int) * (size_t)E);
    unsigned short* Wf1        = (unsigned short*)carve(2 * (size_t)NFEATS * NHIDS);
    unsigned short* Wf2        = (unsigned short*)carve(2 * (size_t)NHIDS * NOUT);
    unsigned short* hs1        = (unsigned short*)carve(2 * (size_t)N * NHIDS);
    unsigned short* hs2        = (unsigned short*)carve(2 * (size_t)N * NOUT);

    const int nbS = (M + 255) / 256;

    // 1. detect + weight pack (fused)
    detect_wpack<<<65, 256, 0, stream>>>(edge, flag, (long long)N, W1, Wf1, W2, Wf2);

    // 2-5. CSR build (chunk_base computed inline by consumers)
    hist_kernel<<<NCH, 512, 0, stream>>>(edge, flag, histT, E, NCH, NBKT);
    scan_block<<<nbS, 256, 0, stream>>>(histT, incl, partial, M);
    scan_partials<<<1, 512, 0, stream>>>(partial, nbS);
    scatter_chunks<<<NCH, 512, 0, stream>>>(edge, flag, histT, incl, partial,
                                            ebuf, E, NCH, NBKT);
    bucket_finalize<<<NBKT, SB, 0, stream>>>(ebuf, histT, incl, partial,
                                             row_ptr, dinv, csr_src, N, E, NCH, NBKT);

    // 6. layer-1 GEMM (needs dinv)
    gemm_mfma<NHIDS, true><<<(N + 127) / 128, 256, 0, stream>>>(x, Wf1, dinv, hs1, N);

    // 7. fused: layer-1 aggregate + ReLU + layer-2 GEMM -> hs2
    aggregate_fused_l1<<<(N + 15) / 16, 256, 0, stream>>>(
        row_ptr, csr_src, (const uint4*)hs1, dinv, b1, Wf2, hs2, N);

    // 8. layer-2 aggregate -> out
    {
        constexpr int NPB = 256 / (NOUT / 8);
        aggregate_bf16<NOUT, false, false><<<(N + NPB - 1) / NPB, 256, 0, stream>>>(
            row_ptr, csr_src, (const uint4*)hs2, dinv, b2, out, N);
    }
}